// Round 1
// baseline (2460.282 us; speedup 1.0000x reference)
//
#include <hip/hip_runtime.h>
#include <hip/hip_cooperative_groups.h>

namespace cg = cooperative_groups;

// Problem constants (match reference)
constexpr int   T_STEPS = 64;
constexpr int   NN      = 2048;
constexpr float DT_TAU  = 0.1f;    // DT * TAU_MEM_INV
constexpr float V_TH_C  = 1.0f;
constexpr float TRC     = 0.05f;   // DT * TAU_PRE_INV == DT * TAU_POST_INV
constexpr float ETA     = 1e-3f;   // ETA_PLUS == ETA_MINUS

// Launch shape: 256 blocks x 512 threads (8 waves). Each block owns 8 rows
// of w (block-private, 64 KB -> stays in its XCD's L2). One wave per row.
constexpr int BLOCKS  = 256;
constexpr int THREADS = 512;
constexpr int ROWS_PER_BLOCK = NN / BLOCKS;   // 8

__global__ __launch_bounds__(THREADS)
void snn_coop_kernel(const float* __restrict__ x,       // [T, N]
                     const float* __restrict__ w_in,    // [N, N] pristine
                     float*       __restrict__ w,       // working copy (may == w_in)
                     const float* __restrict__ tpre0,   // [N]
                     const float* __restrict__ tpost0,  // [N]
                     float*       __restrict__ isyn,    // [2, N] ping-pong (global)
                     float*       __restrict__ out)     // [T, N] spikes
{
    cg::grid_group grid = cg::this_grid();
    const int bid  = blockIdx.x;
    const int tid  = threadIdx.x;
    const int wv   = tid >> 6;    // wave id 0..7 -> row within block
    const int lane = tid & 63;

    // Replicated neuron state, identical (bitwise) across all blocks.
    __shared__ __align__(16) float v_s[NN];
    __shared__ __align__(16) float z_s[NN];
    __shared__ __align__(16) float tp_s[NN];
    __shared__ __align__(16) float tpo_s[NN];

    for (int i = tid; i < NN; i += THREADS) {
        v_s[i]   = 0.0f;
        z_s[i]   = 0.0f;
        tp_s[i]  = tpre0[i];   // zeros per setup, but honor the input
        tpo_s[i] = tpost0[i];
    }

    // Stage this block's private rows of w into the working buffer.
    const int row0 = bid * ROWS_PER_BLOCK;
    if (w != w_in) {
        const float4* src = (const float4*)(w_in + (size_t)row0 * NN);
        float4*       dst = (float4*)(w + (size_t)row0 * NN);
        for (int k = tid; k < ROWS_PER_BLOCK * NN / 4; k += THREADS) dst[k] = src[k];
    }
    __syncthreads();

    for (int t = 0; t < T_STEPS; ++t) {
        // ---- neuron update (redundant in every block; inputs identical) ----
        const float* isyn_cur = isyn + (size_t)(t & 1) * NN;
        const float* xt       = x + (size_t)t * NN;
        for (int i = tid; i < NN; i += THREADS) {
            float is = (t == 0) ? 0.0f : isyn_cur[i];
            float v  = v_s[i];
            v = v + DT_TAU * ((0.0f - v) + is + xt[i]);        // LIF integrate
            float z = (v - V_TH_C > 0.0f) ? 1.0f : 0.0f;       // spike
            v = v * (1.0f - z);                                // reset (V_RESET=0)
            float tp  = tp_s[i];  tp  = tp  + TRC * (-tp  + z);
            float tpo = tpo_s[i]; tpo = tpo + TRC * (-tpo + z);
            v_s[i] = v; z_s[i] = z; tp_s[i] = tp; tpo_s[i] = tpo;
        }
        __syncthreads();

        // ---- spike raster output (one block writes; all have identical z) ----
        if (bid == 0) {
            for (int i = tid; i < NN; i += THREADS) out[(size_t)t * NN + i] = z_s[i];
        }

        // ---- fused STDP weight update + next-step matvec over owned rows ----
        const int   row  = row0 + wv;
        const float zi   = z_s[row];
        const float tpoi = tpo_s[row];
        float acc = 0.0f;
        float4*       wrow = (float4*)(w + (size_t)row * NN);
        const float4* z4   = (const float4*)z_s;
        const float4* tp4  = (const float4*)tp_s;
        #pragma unroll
        for (int k0 = 0; k0 < NN / 4; k0 += 64) {
            const int k = k0 + lane;
            float4 wq  = wrow[k];
            float4 zj  = z4[k];
            float4 tpj = tp4[k];
            float nw;
            nw = wq.x + (ETA * (zi * tpj.x) - ETA * (tpoi * zj.x));
            nw = fminf(fmaxf(nw, 0.0f), 1.0f); wq.x = nw; acc += nw * zj.x;
            nw = wq.y + (ETA * (zi * tpj.y) - ETA * (tpoi * zj.y));
            nw = fminf(fmaxf(nw, 0.0f), 1.0f); wq.y = nw; acc += nw * zj.y;
            nw = wq.z + (ETA * (zi * tpj.z) - ETA * (tpoi * zj.z));
            nw = fminf(fmaxf(nw, 0.0f), 1.0f); wq.z = nw; acc += nw * zj.z;
            nw = wq.w + (ETA * (zi * tpj.w) - ETA * (tpoi * zj.w));
            nw = fminf(fmaxf(nw, 0.0f), 1.0f); wq.w = nw; acc += nw * zj.w;
            wrow[k] = wq;
        }
        // wave-wide reduce -> i_syn for next step (ping-pong buffer)
        #pragma unroll
        for (int m = 32; m >= 1; m >>= 1) acc += __shfl_xor(acc, m, 64);
        if (lane == 0) isyn[(size_t)((t + 1) & 1) * NN + row] = acc;

        grid.sync();   // publish i_syn to all blocks; only barrier per step
    }
}

extern "C" void kernel_launch(void* const* d_in, const int* in_sizes, int n_in,
                              void* d_out, int out_size, void* d_ws, size_t ws_size,
                              hipStream_t stream) {
    const float* x     = (const float*)d_in[0];   // [T,N]
    const float* w_in  = (const float*)d_in[1];   // [N,N]
    const float* tpre  = (const float*)d_in[2];   // [N]
    const float* tpost = (const float*)d_in[3];   // [N]
    float*       out   = (float*)d_out;           // [T,N]

    const size_t w_bytes    = (size_t)NN * NN * sizeof(float);
    const size_t isyn_bytes = 2 * (size_t)NN * sizeof(float);

    float* w_work;
    float* isyn;
    if (ws_size >= w_bytes + isyn_bytes) {
        w_work = (float*)d_ws;
        isyn   = (float*)((char*)d_ws + w_bytes);
    } else {
        // Not enough workspace: update w in place. Harness restores inputs
        // from a pristine copy before every timed launch, so this is safe.
        w_work = const_cast<float*>(w_in);
        isyn   = (float*)d_ws;
    }

    void* args[] = {(void*)&x, (void*)&w_in, (void*)&w_work,
                    (void*)&tpre, (void*)&tpost, (void*)&isyn, (void*)&out};
    hipLaunchCooperativeKernel((void*)snn_coop_kernel,
                               dim3(BLOCKS), dim3(THREADS),
                               args, 0, stream);
}

// Round 2
// 798.090 us; speedup vs baseline: 3.0827x; 3.0827x over previous
//
#include <hip/hip_runtime.h>
#include <hip/hip_cooperative_groups.h>

// Problem constants (match reference)
constexpr int   T_STEPS = 64;
constexpr int   NN      = 2048;
constexpr float DT_TAU  = 0.1f;    // DT * TAU_MEM_INV
constexpr float V_TH_C  = 1.0f;
constexpr float TRC     = 0.05f;   // DT * TAU_PRE_INV == DT * TAU_POST_INV
constexpr float ETA     = 1e-3f;   // ETA_PLUS == ETA_MINUS

// 256 blocks x 512 threads. Each block owns 8 rows of w, one row per wave,
// 32 w elements per lane -> the ENTIRE 16 MB weight matrix lives in VGPRs.
constexpr int BLOCKS  = 256;
constexpr int THREADS = 512;
constexpr int ROWS_PER_BLOCK = NN / BLOCKS;   // 8
constexpr int CHUNKS = NN / 256;              // 8 float4 chunks per lane

__global__ __launch_bounds__(THREADS)
void snn_reg_kernel(const float* __restrict__ x,       // [T, N]
                    const float* __restrict__ w_in,    // [N, N] pristine
                    const float* __restrict__ tpre0,   // [N]
                    const float* __restrict__ tpost0,  // [N]
                    float*       __restrict__ isyn,    // [2, N] ping-pong (ws)
                    unsigned*    __restrict__ bar,     // [0]=count, [1]=gen (ws, zeroed)
                    float*       __restrict__ out)     // [T, N] spikes
{
    const int bid  = blockIdx.x;
    const int tid  = threadIdx.x;
    const int wv   = tid >> 6;
    const int lane = tid & 63;
    const int row  = bid * ROWS_PER_BLOCK + wv;   // this wave's w row

    // Replicated neuron state shared within the block (identical across blocks).
    __shared__ __align__(16) float z_s[NN];
    __shared__ __align__(16) float tp_s[NN];
    __shared__ __align__(16) float tpo_s[NN];

    // Per-thread neuron state: neurons 4*tid .. 4*tid+3 (replicated per block).
    float4 v4   = {0.f, 0.f, 0.f, 0.f};
    float4 tp4  = ((const float4*)tpre0)[tid];
    float4 tpo4 = ((const float4*)tpost0)[tid];

    // This wave's w row into registers: chunk c holds w[row][c*256 + 4*lane .. +3].
    const float4* wrow4 = (const float4*)(w_in + (size_t)row * NN);
    float4 wreg[CHUNKS];
    #pragma unroll
    for (int c = 0; c < CHUNKS; ++c) wreg[c] = wrow4[c * 64 + lane];

    for (int t = 0; ; ++t) {
        // ---- neuron phase (redundant in every block; inputs identical) ----
        const float* isyn_cur = isyn + (size_t)(t & 1) * NN;
        float4 x4 = ((const float4*)(x + (size_t)t * NN))[tid];
        float4 is4 = {0.f, 0.f, 0.f, 0.f};
        if (t > 0) {
            is4.x = __hip_atomic_load(&isyn_cur[4 * tid + 0], __ATOMIC_RELAXED, __HIP_MEMORY_SCOPE_AGENT);
            is4.y = __hip_atomic_load(&isyn_cur[4 * tid + 1], __ATOMIC_RELAXED, __HIP_MEMORY_SCOPE_AGENT);
            is4.z = __hip_atomic_load(&isyn_cur[4 * tid + 2], __ATOMIC_RELAXED, __HIP_MEMORY_SCOPE_AGENT);
            is4.w = __hip_atomic_load(&isyn_cur[4 * tid + 3], __ATOMIC_RELAXED, __HIP_MEMORY_SCOPE_AGENT);
        }
        float4 z4;
        {
            float v, z;
            v = v4.x + DT_TAU * ((0.0f - v4.x) + is4.x + x4.x);
            z = (v - V_TH_C > 0.0f) ? 1.0f : 0.0f; v4.x = v * (1.0f - z); z4.x = z;
            tp4.x  = tp4.x  + TRC * (-tp4.x  + z);
            tpo4.x = tpo4.x + TRC * (-tpo4.x + z);

            v = v4.y + DT_TAU * ((0.0f - v4.y) + is4.y + x4.y);
            z = (v - V_TH_C > 0.0f) ? 1.0f : 0.0f; v4.y = v * (1.0f - z); z4.y = z;
            tp4.y  = tp4.y  + TRC * (-tp4.y  + z);
            tpo4.y = tpo4.y + TRC * (-tpo4.y + z);

            v = v4.z + DT_TAU * ((0.0f - v4.z) + is4.z + x4.z);
            z = (v - V_TH_C > 0.0f) ? 1.0f : 0.0f; v4.z = v * (1.0f - z); z4.z = z;
            tp4.z  = tp4.z  + TRC * (-tp4.z  + z);
            tpo4.z = tpo4.z + TRC * (-tpo4.z + z);

            v = v4.w + DT_TAU * ((0.0f - v4.w) + is4.w + x4.w);
            z = (v - V_TH_C > 0.0f) ? 1.0f : 0.0f; v4.w = v * (1.0f - z); z4.w = z;
            tp4.w  = tp4.w  + TRC * (-tp4.w  + z);
            tpo4.w = tpo4.w + TRC * (-tpo4.w + z);
        }
        ((float4*)z_s)[tid]   = z4;
        ((float4*)tp_s)[tid]  = tp4;
        ((float4*)tpo_s)[tid] = tpo4;
        if (bid == 0) ((float4*)(out + (size_t)t * NN))[tid] = z4;  // spike raster
        __syncthreads();

        if (t == T_STEPS - 1) break;   // last step: no weight pass / barrier needed

        // ---- fused STDP weight update (registers) + next-step matvec ----
        const float zi   = z_s[row];
        const float tpoi = tpo_s[row];
        float acc = 0.0f;
        const float4* z4s  = (const float4*)z_s;
        const float4* tp4s = (const float4*)tp_s;
        #pragma unroll
        for (int c = 0; c < CHUNKS; ++c) {
            float4 zj = z4s[c * 64 + lane];
            float4 tj = tp4s[c * 64 + lane];
            float nw;
            nw = wreg[c].x + (ETA * (zi * tj.x) - ETA * (tpoi * zj.x));
            nw = fminf(fmaxf(nw, 0.0f), 1.0f); wreg[c].x = nw; acc += nw * zj.x;
            nw = wreg[c].y + (ETA * (zi * tj.y) - ETA * (tpoi * zj.y));
            nw = fminf(fmaxf(nw, 0.0f), 1.0f); wreg[c].y = nw; acc += nw * zj.y;
            nw = wreg[c].z + (ETA * (zi * tj.z) - ETA * (tpoi * zj.z));
            nw = fminf(fmaxf(nw, 0.0f), 1.0f); wreg[c].z = nw; acc += nw * zj.z;
            nw = wreg[c].w + (ETA * (zi * tj.w) - ETA * (tpoi * zj.w));
            nw = fminf(fmaxf(nw, 0.0f), 1.0f); wreg[c].w = nw; acc += nw * zj.w;
        }
        #pragma unroll
        for (int m = 32; m >= 1; m >>= 1) acc += __shfl_xor(acc, m, 64);
        if (lane == 0) {
            // straight to the coherence point (sc0 sc1) — no cache-wide flush needed
            __hip_atomic_store(&isyn[(size_t)((t + 1) & 1) * NN + row], acc,
                               __ATOMIC_RELAXED, __HIP_MEMORY_SCOPE_AGENT);
        }
        // __syncthreads emits s_waitcnt vmcnt(0) before s_barrier -> all 8 waves'
        // isyn stores have reached the coherence point before the arrival below.
        __syncthreads();

        // ---- lightweight grid barrier (replaces grid.sync's full L2 flush) ----
        if (tid == 0) {
            const unsigned target = (unsigned)(t + 1);
            unsigned old = __hip_atomic_fetch_add(&bar[0], 1u, __ATOMIC_RELEASE,
                                                  __HIP_MEMORY_SCOPE_AGENT);
            if (old == target * (unsigned)BLOCKS - 1u) {
                __hip_atomic_store(&bar[1], target, __ATOMIC_RELEASE,
                                   __HIP_MEMORY_SCOPE_AGENT);
            } else {
                while (__hip_atomic_load(&bar[1], __ATOMIC_ACQUIRE,
                                         __HIP_MEMORY_SCOPE_AGENT) < target) {}
            }
        }
        __syncthreads();
    }
}

extern "C" void kernel_launch(void* const* d_in, const int* in_sizes, int n_in,
                              void* d_out, int out_size, void* d_ws, size_t ws_size,
                              hipStream_t stream) {
    const float* x     = (const float*)d_in[0];   // [T,N]
    const float* w_in  = (const float*)d_in[1];   // [N,N]
    const float* tpre  = (const float*)d_in[2];   // [N]
    const float* tpost = (const float*)d_in[3];   // [N]
    float*       out   = (float*)d_out;           // [T,N]

    // ws layout: isyn ping-pong (16 KB) | barrier (2 x u32)
    float*    isyn = (float*)d_ws;
    unsigned* bar  = (unsigned*)((char*)d_ws + 2 * NN * sizeof(float));

    // ws is poisoned 0xAA before every timed launch — barrier must start at 0.
    // isyn needs no init (t==0 path uses literal zero).
    hipMemsetAsync(bar, 0, 2 * sizeof(unsigned), stream);

    void* args[] = {(void*)&x, (void*)&w_in, (void*)&tpre, (void*)&tpost,
                    (void*)&isyn, (void*)&bar, (void*)&out};
    hipLaunchCooperativeKernel((void*)snn_reg_kernel,
                               dim3(BLOCKS), dim3(THREADS),
                               args, 0, stream);
}

// Round 3
// 311.934 us; speedup vs baseline: 7.8872x; 2.5585x over previous
//
#include <hip/hip_runtime.h>

// Problem constants (match reference)
constexpr int   T_STEPS = 64;
constexpr int   NN      = 2048;
constexpr float DT_TAU  = 0.1f;    // DT * TAU_MEM_INV
constexpr float V_TH_C  = 1.0f;
constexpr float TRC     = 0.05f;   // DT * TAU_PRE_INV == DT * TAU_POST_INV
constexpr float ETA     = 1e-3f;   // ETA_PLUS == ETA_MINUS

// 256 blocks x 512 threads (cooperative, 1 block/CU). Block b owns neurons
// [8b, 8b+8): their w rows (registers, 32 VGPR/lane), v, tpo. z and tp are
// replicated per block, reconstructed each step from the published spike bits.
// Cross-block traffic per step: ONE u64 per block (8 spike bits + step tag).
constexpr int BLOCKS  = 256;
constexpr int THREADS = 512;
constexpr int ROWS_PER_BLOCK = NN / BLOCKS;   // 8
constexpr int CHUNKS = NN / 256;              // 8 float4 chunks per lane

__global__ __launch_bounds__(THREADS)
void snn_msg_kernel(const float* __restrict__ x,       // [T, N]
                    const float* __restrict__ w_in,    // [N, N] pristine (never written)
                    const float* __restrict__ tpre0,   // [N]
                    const float* __restrict__ tpost0,  // [N]
                    unsigned long long* __restrict__ zpub, // [2][BLOCKS] tag|bits (ws)
                    float*       __restrict__ out)     // [T, N] spikes
{
    const int bid  = blockIdx.x;
    const int tid  = threadIdx.x;
    const int wv   = tid >> 6;
    const int lane = tid & 63;
    const int row  = bid * ROWS_PER_BLOCK + wv;   // this wave's w row / owned neuron

    __shared__ __align__(16) float z_s[NN];       // replicated spike vector
    __shared__ __align__(16) float tp_s[NN];      // replicated pre-trace
    __shared__ float tpo_s8[ROWS_PER_BLOCK];      // owned post-traces
    __shared__ float isyn_s8[ROWS_PER_BLOCK];     // owned synaptic currents (local!)
    __shared__ unsigned zw_s[BLOCKS];             // polled spike words

    // Replicated tp in registers (neurons 4*tid..4*tid+3), mirrored to LDS.
    float4 tp4 = ((const float4*)tpre0)[tid];
    ((float4*)tp_s)[tid] = tp4;

    // Owner state on threads 0..7 (wave 0): v, tpo, prefetched x.
    float v_own = 0.0f, tpo_own = 0.0f, x_own = 0.0f;
    if (tid < ROWS_PER_BLOCK) {
        tpo_own = tpost0[bid * ROWS_PER_BLOCK + tid];
        isyn_s8[tid] = 0.0f;                       // step 0: i_syn = w @ 0 = 0
        x_own = x[bid * ROWS_PER_BLOCK + tid];     // x[0][owned]
    }

    // This wave's w row into registers: chunk c holds w[row][(c*64+lane)*4 ..+3].
    const float4* wrow4 = (const float4*)(w_in + (size_t)row * NN);
    float4 wreg[CHUNKS];
    #pragma unroll
    for (int c = 0; c < CHUNKS; ++c) wreg[c] = wrow4[c * 64 + lane];

    __syncthreads();

    for (int t = 0; t < T_STEPS; ++t) {
        const int par = t & 1;

        // ---- phase A: owners integrate v, spike, publish (wave 0 only) ----
        if (tid < 64) {
            float z = 0.0f;
            if (tid < ROWS_PER_BLOCK) {
                float v = v_own;
                v = v + DT_TAU * ((0.0f - v) + isyn_s8[tid] + x_own);   // LIF
                z = (v - V_TH_C > 0.0f) ? 1.0f : 0.0f;                  // spike
                v_own = v * (1.0f - z);                                 // reset
                tpo_own = tpo_own + TRC * (-tpo_own + z);               // post-trace
                tpo_s8[tid] = tpo_own;
            }
            unsigned long long bits = __ballot(z > 0.0f) & 0xFFull;
            if (tid == 0) {
                unsigned long long word =
                    ((unsigned long long)(unsigned)t << 32) | bits;
                // message == data: single 8B atomic store, tag certifies payload
                __hip_atomic_store(&zpub[par * BLOCKS + bid], word,
                                   __ATOMIC_RELAXED, __HIP_MEMORY_SCOPE_AGENT);
            }
            if (tid < ROWS_PER_BLOCK) {  // prefetch next step's input current
                int tn = (t + 1 < T_STEPS) ? t + 1 : t;
                x_own = x[(size_t)tn * NN + bid * ROWS_PER_BLOCK + tid];
            }
        }

        // ---- phase B: poll all 256 words for this step's tag ----
        if (tid < BLOCKS) {
            unsigned long long v;
            do {
                v = __hip_atomic_load(&zpub[par * BLOCKS + tid],
                                      __ATOMIC_RELAXED, __HIP_MEMORY_SCOPE_AGENT);
            } while ((unsigned)(v >> 32) != (unsigned)t);
            zw_s[tid] = (unsigned)v;   // low 8 bits = z of neurons 8*tid..8*tid+7
        }
        __syncthreads();

        // unpack spikes, update replicated pre-trace, write output raster
        {
            unsigned wbits = zw_s[tid >> 1];
            int sh = (tid & 1) * 4;
            float4 z4;
            z4.x = ((wbits >> (sh + 0)) & 1u) ? 1.0f : 0.0f;
            z4.y = ((wbits >> (sh + 1)) & 1u) ? 1.0f : 0.0f;
            z4.z = ((wbits >> (sh + 2)) & 1u) ? 1.0f : 0.0f;
            z4.w = ((wbits >> (sh + 3)) & 1u) ? 1.0f : 0.0f;
            ((float4*)z_s)[tid] = z4;
            tp4.x = tp4.x + TRC * (-tp4.x + z4.x);
            tp4.y = tp4.y + TRC * (-tp4.y + z4.y);
            tp4.z = tp4.z + TRC * (-tp4.z + z4.z);
            tp4.w = tp4.w + TRC * (-tp4.w + z4.w);
            ((float4*)tp_s)[tid] = tp4;
            if (bid == 0) ((float4*)(out + (size_t)t * NN))[tid] = z4;
        }
        __syncthreads();

        if (t == T_STEPS - 1) break;   // raster written; no further state needed

        // ---- phase C: fused STDP w-update (registers) + matvec for t+1 ----
        const float zi   = z_s[row];
        const float tpoi = tpo_s8[wv];
        float acc = 0.0f;
        const float4* z4s  = (const float4*)z_s;
        const float4* tp4s = (const float4*)tp_s;
        #pragma unroll
        for (int c = 0; c < CHUNKS; ++c) {
            float4 zj = z4s[c * 64 + lane];
            float4 tj = tp4s[c * 64 + lane];
            float nw;
            nw = wreg[c].x + (ETA * (zi * tj.x) - ETA * (tpoi * zj.x));
            nw = fminf(fmaxf(nw, 0.0f), 1.0f); wreg[c].x = nw; acc += nw * zj.x;
            nw = wreg[c].y + (ETA * (zi * tj.y) - ETA * (tpoi * zj.y));
            nw = fminf(fmaxf(nw, 0.0f), 1.0f); wreg[c].y = nw; acc += nw * zj.y;
            nw = wreg[c].z + (ETA * (zi * tj.z) - ETA * (tpoi * zj.z));
            nw = fminf(fmaxf(nw, 0.0f), 1.0f); wreg[c].z = nw; acc += nw * zj.z;
            nw = wreg[c].w + (ETA * (zi * tj.w) - ETA * (tpoi * zj.w));
            nw = fminf(fmaxf(nw, 0.0f), 1.0f); wreg[c].w = nw; acc += nw * zj.w;
        }
        #pragma unroll
        for (int m = 32; m >= 1; m >>= 1) acc += __shfl_xor(acc, m, 64);
        if (lane == 0) isyn_s8[wv] = acc;   // i_syn for step t+1 — stays in LDS
        __syncthreads();                    // isyn_s8/next-A ordering
    }
}

extern "C" void kernel_launch(void* const* d_in, const int* in_sizes, int n_in,
                              void* d_out, int out_size, void* d_ws, size_t ws_size,
                              hipStream_t stream) {
    const float* x     = (const float*)d_in[0];   // [T,N]
    const float* w_in  = (const float*)d_in[1];   // [N,N]
    const float* tpre  = (const float*)d_in[2];   // [N]
    const float* tpost = (const float*)d_in[3];   // [N]
    float*       out   = (float*)d_out;           // [T,N]

    // ws: zpub[2][256] u64 = 4 KB. 0xAA poison (tag 0xAAAAAAAA) never matches
    // a real tag (0..63), and parity double-buffering prevents overwrite of
    // unconsumed words — no initialization needed at all.
    unsigned long long* zpub = (unsigned long long*)d_ws;

    void* args[] = {(void*)&x, (void*)&w_in, (void*)&tpre, (void*)&tpost,
                    (void*)&zpub, (void*)&out};
    hipLaunchCooperativeKernel((void*)snn_msg_kernel,
                               dim3(BLOCKS), dim3(THREADS),
                               args, 0, stream);
}